// Round 9
// baseline (360.571 us; speedup 1.0000x reference)
//
#include <hip/hip_runtime.h>
#include <hip/hip_bf16.h>

typedef __attribute__((ext_vector_type(8))) short bf16x8;
typedef __attribute__((ext_vector_type(4))) float f32x4;

#define DEV static __device__ __forceinline__

DEV unsigned short f2bf(float f) {
    __hip_bfloat16 h = __float2bfloat16(f);
    return __builtin_bit_cast(unsigned short, h);
}
DEV float bf2f(unsigned short s) {
    union { unsigned int u; float f; } v; v.u = ((unsigned int)s) << 16; return v.f;
}
DEV bf16x8 ld_bf8(const unsigned short* p) { return *reinterpret_cast<const bf16x8*>(p); }
DEV f32x4 mfma16(bf16x8 a, bf16x8 b, f32x4 c) {
    return __builtin_amdgcn_mfma_f32_16x16x32_bf16(a, b, c, 0, 0, 0);
}

#define SCALE_L2E (0.125f * 1.44269504088896340736f)

// ---------------- K1: qkv GEMM + bias + RoPE (r6/r8-validated) ----------------
__global__ __launch_bounds__(256) void k_qkv(
    const float* __restrict__ xf, const float* __restrict__ wf,
    const float* __restrict__ bias,
    unsigned short* __restrict__ Qb, unsigned short* __restrict__ Kb,
    unsigned short* __restrict__ Vt)
{
    __shared__ unsigned short As[64][40];
    __shared__ unsigned short Bs[64][40];
    const int m0 = blockIdx.x * 64, c0 = blockIdx.y * 64;
    const int t = threadIdx.x;
    const int w = t >> 6, lane = t & 63, li = lane & 15, lg = lane >> 4;
    const int wr = w >> 1, wc = w & 1;
    f32x4 acc[2][2] = {};
    const int srow = t >> 2, spart = (t & 3) * 8;
    for (int kt = 0; kt < 512; kt += 32) {
        const float* xs = &xf[(size_t)(m0 + srow) * 512 + kt + spart];
        float4 a0 = *(const float4*)xs, a1 = *(const float4*)(xs + 4);
        const float* wsrc = &wf[(size_t)(c0 + srow) * 512 + kt + spart];
        float4 b0 = *(const float4*)wsrc, b1 = *(const float4*)(wsrc + 4);
        ushort4 ua0 = { f2bf(a0.x), f2bf(a0.y), f2bf(a0.z), f2bf(a0.w) };
        ushort4 ua1 = { f2bf(a1.x), f2bf(a1.y), f2bf(a1.z), f2bf(a1.w) };
        ushort4 ub0 = { f2bf(b0.x), f2bf(b0.y), f2bf(b0.z), f2bf(b0.w) };
        ushort4 ub1 = { f2bf(b1.x), f2bf(b1.y), f2bf(b1.z), f2bf(b1.w) };
        *(ushort4*)&As[srow][spart] = ua0; *(ushort4*)&As[srow][spart + 4] = ua1;
        *(ushort4*)&Bs[srow][spart] = ub0; *(ushort4*)&Bs[srow][spart + 4] = ub1;
        __syncthreads();
        bf16x8 af[2], bfr[2];
        #pragma unroll
        for (int mf = 0; mf < 2; mf++) af[mf] = ld_bf8(&As[wr*32 + mf*16 + li][lg*8]);
        #pragma unroll
        for (int nf = 0; nf < 2; nf++) bfr[nf] = ld_bf8(&Bs[wc*32 + nf*16 + li][lg*8]);
        #pragma unroll
        for (int mf = 0; mf < 2; mf++)
            #pragma unroll
            for (int nf = 0; nf < 2; nf++)
                acc[mf][nf] = mfma16(af[mf], bfr[nf], acc[mf][nf]);
        __syncthreads();
    }
    const int type = c0 >> 9;
    const int head = (c0 & 511) >> 6;
    const float b0s = bias[c0 + wc*32 + li];
    const float b1s = bias[c0 + wc*32 + 16 + li];
    float invf = 0.f;
    if (type < 2) invf = powf(10000.f, -(float)li * (1.f/16.f));
    #pragma unroll
    for (int mf = 0; mf < 2; mf++) {
        #pragma unroll
        for (int r = 0; r < 4; r++) {
            int grow = m0 + wr*32 + mf*16 + lg*4 + r;
            int tok = grow & 2047, bb = grow >> 11;
            float v0 = acc[mf][0][r] + b0s;
            float v1 = acc[mf][1][r] + b1s;
            if (type < 2) {
                float ang = (wc == 0 ? (float)(tok & 255) : (float)(tok >> 8)) * invf;
                float s, c;
                sincosf(ang, &s, &c);
                float r0 = v0 * c - v1 * s;
                float r1 = v0 * s + v1 * c;
                unsigned short* dst = (type == 0 ? Qb : Kb);
                size_t base = (((size_t)(bb*8 + head)) * 2048 + tok) * 64 + wc*32 + li;
                dst[base]      = f2bf(r0);
                dst[base + 16] = f2bf(r1);
            } else {
                size_t base = (((size_t)(bb*8 + head)) * 64 + wc*32 + li) * 2048 + tok;
                Vt[base]             = f2bf(v0);
                Vt[base + 16 * 2048] = f2bf(v1);
            }
        }
    }
}

// Stage Q tile for all 8 heads into LDS: Qlds[h][16 i][72 pad]
#define STAGE_Q() do { \
    for (int v = threadIdx.x; v < 1024; v += 512) { \
        int h_ = v >> 7, rest_ = v & 127, i_ = rest_ >> 3, ch_ = rest_ & 7; \
        *(uint4*)&Qlds[h_][i_][ch_*8] = \
            *(const uint4*)&Qb[(((size_t)(bb*8 + h_))*2048 + i0 + i_)*64 + ch_*8]; \
    } \
} while (0)

// Swapped QK: sT[h] = S^T tile; lane holds (i = li, j = js + jt*16 + lg*4 + r)
#define QK_SWAPPED(JT) do { \
    _Pragma("unroll") for (int h = 0; h < 8; h++) { \
        const unsigned short* kp_ = Kbase + ((size_t)h*2048 + js + (JT)*16 + li)*64; \
        bf16x8 k0_ = ld_bf8(kp_ + lg*8), k1_ = ld_bf8(kp_ + 32 + lg*8); \
        bf16x8 q0_ = ld_bf8(&Qlds[h][li][lg*8]); \
        bf16x8 q1_ = ld_bf8(&Qlds[h][li][32 + lg*8]); \
        f32x4 z_ = {}; \
        z_ = mfma16(k0_, q0_, z_); \
        sT[h] = mfma16(k1_, q1_, z_); \
    } \
} while (0)

// ---------------- K2: pass 1 — l[a][i] partial sums, barrier-free main loop ------
// grid 1024: virt = [bb(1) | jq(2) | it(7)], XCD-swizzled; 8 waves each own 32-j slices.
__global__ __launch_bounds__(512) void k_lsum(
    const unsigned short* __restrict__ Qb, const unsigned short* __restrict__ Kb,
    const float* __restrict__ w_pre, float* __restrict__ Lp)
{
    __shared__ unsigned short Qlds[8][16][72];
    __shared__ float Red2[8][16][9];
    const int orig = blockIdx.x;
    const int virt = ((orig & 7) << 7) | (orig >> 3);
    const int it = virt & 127, jq = (virt >> 7) & 3, bb = virt >> 9;
    const int i0 = it * 16;
    const int tid = threadIdx.x, w = tid >> 6, lane = tid & 63, li = lane & 15, lg = lane >> 4;
    STAGE_Q();
    __syncthreads();
    const unsigned short* Kbase = Kb + (size_t)bb * 8 * 2048 * 64;
    float lacc[8] = {};
    #pragma unroll 1
    for (int s = 0; s < 2; s++) {
        const int js = jq*512 + s*256 + w*32;
        #pragma unroll
        for (int jt = 0; jt < 2; jt++) {
            f32x4 sT[8];
            QK_SWAPPED(jt);
            #pragma unroll
            for (int r = 0; r < 4; r++)
                #pragma unroll
                for (int a = 0; a < 8; a++) {
                    float t = 0.f;
                    #pragma unroll
                    for (int h = 0; h < 8; h++) t = fmaf(w_pre[a*8 + h], sT[h][r], t);
                    lacc[a] += __builtin_amdgcn_exp2f(t * SCALE_L2E);
                }
        }
    }
    #pragma unroll
    for (int a = 0; a < 8; a++) {
        lacc[a] += __shfl_xor(lacc[a], 16);
        lacc[a] += __shfl_xor(lacc[a], 32);
    }
    if (lg == 0) {
        #pragma unroll
        for (int a = 0; a < 8; a++) Red2[w][li][a] = lacc[a];
    }
    __syncthreads();
    if (tid < 128) {
        const int i_ = tid >> 3, a_ = tid & 7;
        float sv = 0.f;
        #pragma unroll
        for (int ww = 0; ww < 8; ww++) sv += Red2[ww][i_][a_];
        Lp[(size_t)jq*32768 + ((size_t)bb*2048 + i0 + i_)*8 + a_] = sv;
    }
}

// ---------------- K3: pass 2 — barrier-free: lane-local mix + in-wave bpermute ----
// transpose to PV A-fragments; per-wave 8-head accumulators; end-of-kernel reduce.
__global__ __launch_bounds__(512, 2) void k_attn(
    const unsigned short* __restrict__ Qb, const unsigned short* __restrict__ Kb,
    const unsigned short* __restrict__ Vt,
    const float* __restrict__ w_pre, const float* __restrict__ w_post,
    const float* __restrict__ Lp,
    unsigned short* __restrict__ AOp0, unsigned short* __restrict__ AOp1)
{
    __shared__ unsigned short Qlds[8][16][72];
    __shared__ float Red[8][16][68];
    const int orig = blockIdx.x;
    const int virt = ((orig & 7) << 6) | (orig >> 3);
    const int it = virt & 127, jh = (virt >> 7) & 1, bb = virt >> 8;
    const int i0 = it * 16;
    const int tid = threadIdx.x, w = tid >> 6, lane = tid & 63, li = lane & 15, lg = lane >> 4;
    STAGE_Q();
    float Llog[8];
    {
        const size_t gL = ((size_t)bb*2048 + i0 + li) * 8;
        #pragma unroll
        for (int a = 0; a < 8; a++)
            Llog[a] = __builtin_amdgcn_logf(
                Lp[gL + a] + Lp[32768 + gL + a] + Lp[65536 + gL + a] + Lp[98304 + gL + a]);
    }
    const unsigned short* Kbase = Kb + (size_t)bb * 8 * 2048 * 64;
    const unsigned short* Vbase = Vt + (size_t)bb * 8 * 64 * 2048;
    __syncthreads();
    // bpermute indices: src lane = (lg&1)*32 + li (and +16); select word by own lg>>1
    const int idx0 = (((lane >> 4) & 1) * 32 + li) * 4;
    const int idx1 = idx0 + 64;
    const bool jthi = (lane & 32) != 0;
    f32x4 oacc[8][4] = {};
    #pragma unroll 1
    for (int s = 0; s < 4; s++) {
        const int js = jh*1024 + s*256 + w*32;
        unsigned pkw[8][4];
        #pragma unroll
        for (int jt = 0; jt < 2; jt++) {
            f32x4 sT[8];
            QK_SWAPPED(jt);
            #pragma unroll
            for (int r = 0; r < 4; r++) {
                float p[8];
                #pragma unroll
                for (int a = 0; a < 8; a++) {
                    float t = 0.f;
                    #pragma unroll
                    for (int h = 0; h < 8; h++) t = fmaf(w_pre[a*8 + h], sT[h][r], t);
                    p[a] = __builtin_amdgcn_exp2f(t * SCALE_L2E - Llog[a]);
                }
                #pragma unroll
                for (int c = 0; c < 8; c++) {
                    float t = 0.f;
                    #pragma unroll
                    for (int a = 0; a < 8; a++) t = fmaf(w_post[c*8 + a], p[a], t);
                    const unsigned bv = f2bf(t);
                    if (r & 1) pkw[c][jt*2 + (r >> 1)] |= (bv << 16);
                    else       pkw[c][jt*2 + (r >> 1)]  = bv;
                }
            }
        }
        // PV: per c build A-frag via 8 bpermute + 4 selects, V double-buffered
        bf16x8 vc[4];
        #pragma unroll
        for (int nf = 0; nf < 4; nf++)
            vc[nf] = ld_bf8(Vbase + ((size_t)(nf*16 + li))*2048 + js + lg*8);
        #pragma unroll
        for (int c = 0; c < 8; c++) {
            bf16x8 vn[4];
            if (c < 7) {
                #pragma unroll
                for (int nf = 0; nf < 4; nf++)
                    vn[nf] = ld_bf8(Vbase + ((size_t)((c+1)*64 + nf*16 + li))*2048 + js + lg*8);
            }
            union { unsigned u[4]; bf16x8 v; } af;
            {
                const int p0 = __builtin_amdgcn_ds_bpermute(idx0, (int)pkw[c][0]);
                const int p2 = __builtin_amdgcn_ds_bpermute(idx0, (int)pkw[c][2]);
                const int p1 = __builtin_amdgcn_ds_bpermute(idx0, (int)pkw[c][1]);
                const int p3 = __builtin_amdgcn_ds_bpermute(idx0, (int)pkw[c][3]);
                const int q0 = __builtin_amdgcn_ds_bpermute(idx1, (int)pkw[c][0]);
                const int q2 = __builtin_amdgcn_ds_bpermute(idx1, (int)pkw[c][2]);
                const int q1 = __builtin_amdgcn_ds_bpermute(idx1, (int)pkw[c][1]);
                const int q3 = __builtin_amdgcn_ds_bpermute(idx1, (int)pkw[c][3]);
                af.u[0] = (unsigned)(jthi ? p2 : p0);
                af.u[1] = (unsigned)(jthi ? p3 : p1);
                af.u[2] = (unsigned)(jthi ? q2 : q0);
                af.u[3] = (unsigned)(jthi ? q3 : q1);
            }
            #pragma unroll
            for (int nf = 0; nf < 4; nf++)
                oacc[c][nf] = mfma16(af.v, vc[nf], oacc[c][nf]);
            if (c < 7) {
                #pragma unroll
                for (int nf = 0; nf < 4; nf++) vc[nf] = vn[nf];
            }
        }
    }
    // cross-wave reduction (only barriers besides Q-staging), then AO write
    unsigned short* ao = jh ? AOp1 : AOp0;
    #pragma unroll 1
    for (int c = 0; c < 8; c++) {
        __syncthreads();
        #pragma unroll
        for (int nf = 0; nf < 4; nf++)
            #pragma unroll
            for (int r = 0; r < 4; r++)
                Red[w][lg*4 + r][nf*16 + li] = oacc[c][nf][r];
        __syncthreads();
        {
            const int i_ = tid >> 6, d_ = tid & 63;   // elements 0..511
            float sv = 0.f;
            #pragma unroll
            for (int ww = 0; ww < 8; ww++) sv += Red[ww][i_][d_];
            ao[((size_t)bb*2048 + i0 + i_)*512 + c*64 + d_] = f2bf(sv);
            const int i2 = (tid + 512) >> 6;          // elements 512..1023
            float sv2 = 0.f;
            #pragma unroll
            for (int ww = 0; ww < 8; ww++) sv2 += Red[ww][i2][d_];
            ao[((size_t)bb*2048 + i0 + i2)*512 + c*64 + d_] = f2bf(sv2);
        }
    }
}

// ---------------- K4: output GEMM, partial-sum + f32-weight cvt fused (validated) --
__global__ __launch_bounds__(256) void k_out(
    const unsigned short* __restrict__ a0, const unsigned short* __restrict__ a1,
    const float* __restrict__ wf, const float* __restrict__ bias,
    float* __restrict__ out)
{
    __shared__ unsigned short As[64][40];
    __shared__ unsigned short Bs[64][40];
    const int m0 = blockIdx.x * 64, c0 = blockIdx.y * 64;
    const int t = threadIdx.x;
    const int w = t >> 6, lane = t & 63, li = lane & 15, lg = lane >> 4;
    const int wr = w >> 1, wc = w & 1;
    f32x4 acc[2][2] = {};
    const int srow = t >> 2, spart = (t & 3) * 8;
    for (int kt = 0; kt < 512; kt += 32) {
        size_t aidx = (size_t)(m0 + srow) * 512 + kt + spart;
        uint4 ua = *(const uint4*)&a0[aidx];
        uint4 ub = *(const uint4*)&a1[aidx];
        const unsigned short* pa = (const unsigned short*)&ua;
        const unsigned short* pb = (const unsigned short*)&ub;
        unsigned short us[8];
        #pragma unroll
        for (int q = 0; q < 8; q++) us[q] = f2bf(bf2f(pa[q]) + bf2f(pb[q]));
        *reinterpret_cast<uint4*>(&As[srow][spart]) = *(const uint4*)us;
        const float* wsrc = &wf[(size_t)(c0 + srow) * 512 + kt + spart];
        float4 b0 = *(const float4*)wsrc, b1 = *(const float4*)(wsrc + 4);
        ushort4 ub0 = { f2bf(b0.x), f2bf(b0.y), f2bf(b0.z), f2bf(b0.w) };
        ushort4 ub1 = { f2bf(b1.x), f2bf(b1.y), f2bf(b1.z), f2bf(b1.w) };
        *(ushort4*)&Bs[srow][spart] = ub0; *(ushort4*)&Bs[srow][spart + 4] = ub1;
        __syncthreads();
        bf16x8 af[2], bfr[2];
        #pragma unroll
        for (int mf = 0; mf < 2; mf++) af[mf] = ld_bf8(&As[wr*32 + mf*16 + li][lg*8]);
        #pragma unroll
        for (int nf = 0; nf < 2; nf++) bfr[nf] = ld_bf8(&Bs[wc*32 + nf*16 + li][lg*8]);
        #pragma unroll
        for (int mf = 0; mf < 2; mf++)
            #pragma unroll
            for (int nf = 0; nf < 2; nf++)
                acc[mf][nf] = mfma16(af[mf], bfr[nf], acc[mf][nf]);
        __syncthreads();
    }
    #pragma unroll
    for (int mf = 0; mf < 2; mf++)
        #pragma unroll
        for (int nf = 0; nf < 2; nf++)
            #pragma unroll
            for (int r = 0; r < 4; r++) {
                int grow = m0 + wr*32 + mf*16 + lg*4 + r;
                int gcol = c0 + wc*32 + nf*16 + li;
                out[(size_t)grow * 512 + gcol] = acc[mf][nf][r] + bias[gcol];
            }
}

extern "C" void kernel_launch(void* const* d_in, const int* in_sizes, int n_in,
                              void* d_out, int out_size, void* d_ws, size_t ws_size,
                              hipStream_t stream)
{
    const float* x      = (const float*)d_in[0];
    const float* w_qkv  = (const float*)d_in[1];
    const float* b_qkv  = (const float*)d_in[2];
    const float* w_pre  = (const float*)d_in[3];
    const float* w_post = (const float*)d_in[4];
    const float* w_out  = (const float*)d_in[5];
    const float* b_out  = (const float*)d_in[6];
    float* out = (float*)d_out;

    char* ws = (char*)d_ws;
    unsigned short* Qb   = (unsigned short*)(ws);               // 4 MB
    unsigned short* Kb   = (unsigned short*)(ws + 4194304);     // 4 MB
    unsigned short* Vt   = (unsigned short*)(ws + 8388608);     // 4 MB
    unsigned short* AOp0 = (unsigned short*)(ws + 12582912);    // 4 MB
    unsigned short* AOp1 = (unsigned short*)(ws + 16777216);    // 4 MB
    float* Lp            = (float*)(ws + 20971520);             // 512 KB (4 j-quarter slabs)

    k_qkv<<<dim3(64, 24), 256, 0, stream>>>(x, w_qkv, b_qkv, Qb, Kb, Vt);
    k_lsum<<<1024, 512, 0, stream>>>(Qb, Kb, w_pre, Lp);
    k_attn<<<512, 512, 0, stream>>>(Qb, Kb, Vt, w_pre, w_post, Lp, AOp0, AOp1);
    k_out<<<dim3(64, 8), 256, 0, stream>>>(AOp0, AOp1, w_out, b_out, out);
}

// Round 10
// 247.731 us; speedup vs baseline: 1.4555x; 1.4555x over previous
//
#include <hip/hip_runtime.h>
#include <hip/hip_bf16.h>

typedef __attribute__((ext_vector_type(8))) short bf16x8;
typedef __attribute__((ext_vector_type(4))) float f32x4;
typedef __attribute__((ext_vector_type(2))) float f32x2;

#define DEV static __device__ __forceinline__

DEV unsigned short f2bf(float f) {
    __hip_bfloat16 h = __float2bfloat16(f);
    return __builtin_bit_cast(unsigned short, h);
}
DEV float bf2f(unsigned short s) {
    union { unsigned int u; float f; } v; v.u = ((unsigned int)s) << 16; return v.f;
}
DEV bf16x8 ld_bf8(const unsigned short* p) { return *reinterpret_cast<const bf16x8*>(p); }
DEV f32x4 mfma16(bf16x8 a, bf16x8 b, f32x4 c) {
    return __builtin_amdgcn_mfma_f32_16x16x32_bf16(a, b, c, 0, 0, 0);
}

#define SCALE_L2E (0.125f * 1.44269504088896340736f)

// ---------------- K1: qkv GEMM + bias + RoPE (r6/r8-validated) ----------------
__global__ __launch_bounds__(256) void k_qkv(
    const float* __restrict__ xf, const float* __restrict__ wf,
    const float* __restrict__ bias,
    unsigned short* __restrict__ Qb, unsigned short* __restrict__ Kb,
    unsigned short* __restrict__ Vt)
{
    __shared__ unsigned short As[64][40];
    __shared__ unsigned short Bs[64][40];
    const int m0 = blockIdx.x * 64, c0 = blockIdx.y * 64;
    const int t = threadIdx.x;
    const int w = t >> 6, lane = t & 63, li = lane & 15, lg = lane >> 4;
    const int wr = w >> 1, wc = w & 1;
    f32x4 acc[2][2] = {};
    const int srow = t >> 2, spart = (t & 3) * 8;
    for (int kt = 0; kt < 512; kt += 32) {
        const float* xs = &xf[(size_t)(m0 + srow) * 512 + kt + spart];
        float4 a0 = *(const float4*)xs, a1 = *(const float4*)(xs + 4);
        const float* wsrc = &wf[(size_t)(c0 + srow) * 512 + kt + spart];
        float4 b0 = *(const float4*)wsrc, b1 = *(const float4*)(wsrc + 4);
        ushort4 ua0 = { f2bf(a0.x), f2bf(a0.y), f2bf(a0.z), f2bf(a0.w) };
        ushort4 ua1 = { f2bf(a1.x), f2bf(a1.y), f2bf(a1.z), f2bf(a1.w) };
        ushort4 ub0 = { f2bf(b0.x), f2bf(b0.y), f2bf(b0.z), f2bf(b0.w) };
        ushort4 ub1 = { f2bf(b1.x), f2bf(b1.y), f2bf(b1.z), f2bf(b1.w) };
        *(ushort4*)&As[srow][spart] = ua0; *(ushort4*)&As[srow][spart + 4] = ua1;
        *(ushort4*)&Bs[srow][spart] = ub0; *(ushort4*)&Bs[srow][spart + 4] = ub1;
        __syncthreads();
        bf16x8 af[2], bfr[2];
        #pragma unroll
        for (int mf = 0; mf < 2; mf++) af[mf] = ld_bf8(&As[wr*32 + mf*16 + li][lg*8]);
        #pragma unroll
        for (int nf = 0; nf < 2; nf++) bfr[nf] = ld_bf8(&Bs[wc*32 + nf*16 + li][lg*8]);
        #pragma unroll
        for (int mf = 0; mf < 2; mf++)
            #pragma unroll
            for (int nf = 0; nf < 2; nf++)
                acc[mf][nf] = mfma16(af[mf], bfr[nf], acc[mf][nf]);
        __syncthreads();
    }
    const int type = c0 >> 9;
    const int head = (c0 & 511) >> 6;
    const float b0s = bias[c0 + wc*32 + li];
    const float b1s = bias[c0 + wc*32 + 16 + li];
    float invf = 0.f;
    if (type < 2) invf = powf(10000.f, -(float)li * (1.f/16.f));
    #pragma unroll
    for (int mf = 0; mf < 2; mf++) {
        #pragma unroll
        for (int r = 0; r < 4; r++) {
            int grow = m0 + wr*32 + mf*16 + lg*4 + r;
            int tok = grow & 2047, bb = grow >> 11;
            float v0 = acc[mf][0][r] + b0s;
            float v1 = acc[mf][1][r] + b1s;
            if (type < 2) {
                float ang = (wc == 0 ? (float)(tok & 255) : (float)(tok >> 8)) * invf;
                float s, c;
                sincosf(ang, &s, &c);
                float r0 = v0 * c - v1 * s;
                float r1 = v0 * s + v1 * c;
                unsigned short* dst = (type == 0 ? Qb : Kb);
                size_t base = (((size_t)(bb*8 + head)) * 2048 + tok) * 64 + wc*32 + li;
                dst[base]      = f2bf(r0);
                dst[base + 16] = f2bf(r1);
            } else {
                size_t base = (((size_t)(bb*8 + head)) * 64 + wc*32 + li) * 2048 + tok;
                Vt[base]             = f2bf(v0);
                Vt[base + 16 * 2048] = f2bf(v1);
            }
        }
    }
}

// Stage Q tile for all 8 heads into LDS: Qlds[h][16 i][72 pad]
#define STAGE_Q() do { \
    for (int v = threadIdx.x; v < 1024; v += 512) { \
        int h_ = v >> 7, rest_ = v & 127, i_ = rest_ >> 3, ch_ = rest_ & 7; \
        *(uint4*)&Qlds[h_][i_][ch_*8] = \
            *(const uint4*)&Qb[(((size_t)(bb*8 + h_))*2048 + i0 + i_)*64 + ch_*8]; \
    } \
} while (0)

// QK^T for all 8 heads: lane holds (j = js+li, i = lg*4+r), acc[h][r]
#define QK_ALLH() do { \
    _Pragma("unroll") for (int h = 0; h < 8; h++) { \
        const unsigned short* kp_ = Kb + (((size_t)(bb*8 + h))*2048 + js + li)*64; \
        bf16x8 k0_ = ld_bf8(kp_ + lg*8), k1_ = ld_bf8(kp_ + 32 + lg*8); \
        bf16x8 q0_ = ld_bf8(&Qlds[h][li][lg*8]); \
        bf16x8 q1_ = ld_bf8(&Qlds[h][li][32 + lg*8]); \
        f32x4 z_ = {}; \
        z_ = mfma16(q0_, k0_, z_); \
        acc[h] = mfma16(q1_, k1_, z_); \
    } \
} while (0)

// ---------------- K2: pass 1 — l[a][i] = sum_j exp2(premix(QK)) ----------------
__global__ __launch_bounds__(512, 4) void k_lsum(
    const unsigned short* __restrict__ Qb, const unsigned short* __restrict__ Kb,
    const float* __restrict__ w_pre, float* __restrict__ Lp)
{
    __shared__ unsigned short Qlds[8][16][72];
    __shared__ float Red[8][128];
    const int orig = blockIdx.x;
    const int virt = ((orig & 7) << 6) | (orig >> 3);
    const int jh = virt & 1, it = (virt >> 1) & 127, bb = virt >> 8;
    const int i0 = it * 16;
    const int tid = threadIdx.x, w = tid >> 6, lane = tid & 63, li = lane & 15, lg = lane >> 4;
    STAGE_Q();
    __syncthreads();
    float lacc[4][8] = {};
    #pragma unroll 1
    for (int s = 0; s < 8; s++) {
        const int js = jh*1024 + s*128 + w*16;
        f32x4 acc[8];
        QK_ALLH();
        #pragma unroll
        for (int r2 = 0; r2 < 2; r2++) {
            #pragma unroll
            for (int a = 0; a < 8; a++) {
                f32x2 t = {0.f, 0.f};
                #pragma unroll
                for (int h = 0; h < 8; h++) {
                    const float wv = w_pre[a*8 + h];
                    t.x = fmaf(wv, acc[h][2*r2], t.x);
                    t.y = fmaf(wv, acc[h][2*r2 + 1], t.y);
                }
                lacc[2*r2][a]     += __builtin_amdgcn_exp2f(t.x * SCALE_L2E);
                lacc[2*r2 + 1][a] += __builtin_amdgcn_exp2f(t.y * SCALE_L2E);
            }
        }
    }
    // reduce over the 16 j-lanes (li bits 0..3)
    #pragma unroll
    for (int m = 1; m <= 8; m <<= 1)
        #pragma unroll
        for (int r = 0; r < 4; r++)
            #pragma unroll
            for (int a = 0; a < 8; a++)
                lacc[r][a] += __shfl_xor(lacc[r][a], m);
    // cross-wave reduction: each wave holds only its 128-j partial
    if (li == 0) {
        #pragma unroll
        for (int r = 0; r < 4; r++)
            #pragma unroll
            for (int a = 0; a < 8; a++)
                Red[w][(lg*4 + r)*8 + a] = lacc[r][a];
    }
    __syncthreads();
    if (tid < 128) {
        float s = 0.f;
        #pragma unroll
        for (int ww = 0; ww < 8; ww++) s += Red[ww][tid];
        float* Lpw = Lp + (size_t)jh * 32768;
        Lpw[((size_t)bb*2048 + i0 + (tid >> 3))*8 + (tid & 7)] = s;
    }
}

// ---------------- K3: pass 2 — r8 structure, half-size Ah (4 blocks/CU), packed mix
__global__ __launch_bounds__(512, 4) void k_attn(
    const unsigned short* __restrict__ Qb, const unsigned short* __restrict__ Kb,
    const unsigned short* __restrict__ Vt,
    const float* __restrict__ w_pre, const float* __restrict__ w_post,
    const float* __restrict__ Lp,
    unsigned short* __restrict__ AOp0, unsigned short* __restrict__ AOp1)
{
    __shared__ unsigned short Qlds[8][16][72];   // 18432 B
    __shared__ unsigned short Ah[4][16][136];    // 17408 B (half the heads per round)
    __shared__ float Llds[128];                  //   512 B -> total 36352 B, 4 blocks/CU
    const int orig = blockIdx.x;
    const int virt = ((orig & 7) << 6) | (orig >> 3);
    const int jh = virt & 1, it = (virt >> 1) & 127, bb = virt >> 8;
    const int i0 = it * 16;
    const int tid = threadIdx.x, w = tid >> 6, lane = tid & 63, li = lane & 15, lg = lane >> 4;
    STAGE_Q();
    if (tid < 128) {
        int i_ = tid >> 3, a_ = tid & 7;
        size_t g = ((size_t)bb*2048 + i0 + i_)*8 + a_;
        Llds[a_*16 + i_] = __builtin_amdgcn_logf(Lp[g] + Lp[32768 + g]);   // log2
    }
    const unsigned short* Vp = Vt + ((size_t)(bb*8 + w)) * 64 * 2048;      // head = w
    __syncthreads();
    f32x4 oacc[4] = {};
    #pragma unroll 1
    for (int s = 0; s < 8; s++) {
        const int j0 = jh*1024 + s*128;
        const int js = j0 + w*16;
        f32x4 acc[8];
        QK_ALLH();
        // lane-local premix -> exp2(normalized) -> postmix, packed over j-row pairs
        unsigned short a2s[4][8];
        #pragma unroll
        for (int r2 = 0; r2 < 2; r2++) {
            f32x2 p2[8];
            #pragma unroll
            for (int a = 0; a < 8; a++) {
                f32x2 t = {0.f, 0.f};
                #pragma unroll
                for (int h = 0; h < 8; h++) {
                    const float wv = w_pre[a*8 + h];
                    t.x = fmaf(wv, acc[h][2*r2], t.x);
                    t.y = fmaf(wv, acc[h][2*r2 + 1], t.y);
                }
                const f32x2 lgv = *(const f32x2*)&Llds[a*16 + lg*4 + 2*r2];
                p2[a].x = __builtin_amdgcn_exp2f(t.x * SCALE_L2E - lgv.x);
                p2[a].y = __builtin_amdgcn_exp2f(t.y * SCALE_L2E - lgv.y);
            }
            #pragma unroll
            for (int c = 0; c < 8; c++) {
                f32x2 t = {0.f, 0.f};
                #pragma unroll
                for (int a = 0; a < 8; a++) {
                    const float wv = w_post[c*8 + a];
                    t.x = fmaf(wv, p2[a].x, t.x);
                    t.y = fmaf(wv, p2[a].y, t.y);
                }
                a2s[2*r2][c]     = f2bf(t.x);
                a2s[2*r2 + 1][c] = f2bf(t.y);
            }
        }
        // round A: heads 0..3
        __syncthreads();               // prior round-B PV reads of Ah done
        #pragma unroll
        for (int r = 0; r < 4; r++)
            #pragma unroll
            for (int c = 0; c < 4; c++)
                Ah[c][lg*4 + r][w*16 + li] = a2s[r][c];
        __syncthreads();
        if (w < 4) {
            #pragma unroll
            for (int kc = 0; kc < 4; kc++) {
                bf16x8 pa = ld_bf8(&Ah[w][li][kc*32 + lg*8]);
                #pragma unroll
                for (int nf = 0; nf < 4; nf++) {
                    bf16x8 vfr = ld_bf8(Vp + (size_t)(nf*16 + li)*2048 + j0 + kc*32 + lg*8);
                    oacc[nf] = mfma16(pa, vfr, oacc[nf]);
                }
            }
        }
        // round B: heads 4..7
        __syncthreads();               // round-A PV reads done
        #pragma unroll
        for (int r = 0; r < 4; r++)
            #pragma unroll
            for (int c = 0; c < 4; c++)
                Ah[c][lg*4 + r][w*16 + li] = a2s[r][c + 4];
        __syncthreads();
        if (w >= 4) {
            #pragma unroll
            for (int kc = 0; kc < 4; kc++) {
                bf16x8 pa = ld_bf8(&Ah[w - 4][li][kc*32 + lg*8]);
                #pragma unroll
                for (int nf = 0; nf < 4; nf++) {
                    bf16x8 vfr = ld_bf8(Vp + (size_t)(nf*16 + li)*2048 + j0 + kc*32 + lg*8);
                    oacc[nf] = mfma16(pa, vfr, oacc[nf]);
                }
            }
        }
    }
    unsigned short* ao = jh ? AOp1 : AOp0;
    #pragma unroll
    for (int nf = 0; nf < 4; nf++)
        #pragma unroll
        for (int r = 0; r < 4; r++)
            ao[((size_t)bb*2048 + i0 + lg*4 + r)*512 + w*64 + nf*16 + li] = f2bf(oacc[nf][r]);
}

// ---------------- K4: output GEMM, partial-sum + f32-weight cvt fused (validated) --
__global__ __launch_bounds__(256) void k_out(
    const unsigned short* __restrict__ a0, const unsigned short* __restrict__ a1,
    const float* __restrict__ wf, const float* __restrict__ bias,
    float* __restrict__ out)
{
    __shared__ unsigned short As[64][40];
    __shared__ unsigned short Bs[64][40];
    const int m0 = blockIdx.x * 64, c0 = blockIdx.y * 64;
    const int t = threadIdx.x;
    const int w = t >> 6, lane = t & 63, li = lane & 15, lg = lane >> 4;
    const int wr = w >> 1, wc = w & 1;
    f32x4 acc[2][2] = {};
    const int srow = t >> 2, spart = (t & 3) * 8;
    for (int kt = 0; kt < 512; kt += 32) {
        size_t aidx = (size_t)(m0 + srow) * 512 + kt + spart;
        uint4 ua = *(const uint4*)&a0[aidx];
        uint4 ub = *(const uint4*)&a1[aidx];
        const unsigned short* pa = (const unsigned short*)&ua;
        const unsigned short* pb = (const unsigned short*)&ub;
        unsigned short us[8];
        #pragma unroll
        for (int q = 0; q < 8; q++) us[q] = f2bf(bf2f(pa[q]) + bf2f(pb[q]));
        *reinterpret_cast<uint4*>(&As[srow][spart]) = *(const uint4*)us;
        const float* wsrc = &wf[(size_t)(c0 + srow) * 512 + kt + spart];
        float4 b0 = *(const float4*)wsrc, b1 = *(const float4*)(wsrc + 4);
        ushort4 ub0 = { f2bf(b0.x), f2bf(b0.y), f2bf(b0.z), f2bf(b0.w) };
        ushort4 ub1 = { f2bf(b1.x), f2bf(b1.y), f2bf(b1.z), f2bf(b1.w) };
        *(ushort4*)&Bs[srow][spart] = ub0; *(ushort4*)&Bs[srow][spart + 4] = ub1;
        __syncthreads();
        bf16x8 af[2], bfr[2];
        #pragma unroll
        for (int mf = 0; mf < 2; mf++) af[mf] = ld_bf8(&As[wr*32 + mf*16 + li][lg*8]);
        #pragma unroll
        for (int nf = 0; nf < 2; nf++) bfr[nf] = ld_bf8(&Bs[wc*32 + nf*16 + li][lg*8]);
        #pragma unroll
        for (int mf = 0; mf < 2; mf++)
            #pragma unroll
            for (int nf = 0; nf < 2; nf++)
                acc[mf][nf] = mfma16(af[mf], bfr[nf], acc[mf][nf]);
        __syncthreads();
    }
    #pragma unroll
    for (int mf = 0; mf < 2; mf++)
        #pragma unroll
        for (int nf = 0; nf < 2; nf++)
            #pragma unroll
            for (int r = 0; r < 4; r++) {
                int grow = m0 + wr*32 + mf*16 + lg*4 + r;
                int gcol = c0 + wc*32 + nf*16 + li;
                out[(size_t)grow * 512 + gcol] = acc[mf][nf][r] + bias[gcol];
            }
}

extern "C" void kernel_launch(void* const* d_in, const int* in_sizes, int n_in,
                              void* d_out, int out_size, void* d_ws, size_t ws_size,
                              hipStream_t stream)
{
    const float* x      = (const float*)d_in[0];
    const float* w_qkv  = (const float*)d_in[1];
    const float* b_qkv  = (const float*)d_in[2];
    const float* w_pre  = (const float*)d_in[3];
    const float* w_post = (const float*)d_in[4];
    const float* w_out  = (const float*)d_in[5];
    const float* b_out  = (const float*)d_in[6];
    float* out = (float*)d_out;

    char* ws = (char*)d_ws;
    unsigned short* Qb   = (unsigned short*)(ws);               // 4 MB
    unsigned short* Kb   = (unsigned short*)(ws + 4194304);     // 4 MB
    unsigned short* Vt   = (unsigned short*)(ws + 8388608);     // 4 MB
    unsigned short* AOp0 = (unsigned short*)(ws + 12582912);    // 4 MB
    unsigned short* AOp1 = (unsigned short*)(ws + 16777216);    // 4 MB
    float* Lp            = (float*)(ws + 20971520);             // 256 KB (2 jh slabs)

    k_qkv<<<dim3(64, 24), 256, 0, stream>>>(x, w_qkv, b_qkv, Qb, Kb, Vt);
    k_lsum<<<512, 512, 0, stream>>>(Qb, Kb, w_pre, Lp);
    k_attn<<<512, 512, 0, stream>>>(Qb, Kb, Vt, w_pre, w_post, Lp, AOp0, AOp1);
    k_out<<<dim3(64, 8), 256, 0, stream>>>(AOp0, AOp1, w_out, b_out, out);
}